// Round 2
// baseline (2128.791 us; speedup 1.0000x reference)
//
#include <hip/hip_runtime.h>

// HSTU block, B=2 S=2048 D=1024 H=8 head=64 L=2. All inputs/outputs fp32.
// Pipeline in d_ws (64 MB fp32): xf(16M) | h/udot(16M) | proj(32M).
#define B_ 2
#define S_ 2048
#define D_ 1024
#define H_ 8
#define L_ 2
#define P_ 2048   // proj dim = 2*DL*H + 2*DA*H
#define F_ 512    // DL*H
#define R_ (B_*S_)

__device__ __forceinline__ float silu(float x){
  return x / (1.0f + __expf(-x));
}

// ---- x copy (fp32 -> fp32 workspace; x is mutated by residuals) ----
__global__ __launch_bounds__(256) void cvt_kernel(const float* __restrict__ x, float* __restrict__ xf){
  int i = (blockIdx.x * 256 + threadIdx.x) * 4;
  *(float4*)(xf + i) = *(const float4*)(x + i);
}

// ---- LayerNorm over D=1024; one block per row ----
__global__ __launch_bounds__(256) void ln_kernel(const float* __restrict__ xf,
    const float* __restrict__ w, const float* __restrict__ b,
    float* __restrict__ outp, float eps){
  int row = blockIdx.x, tid = threadIdx.x;
  const float* xr = xf + (size_t)row * D_;
  float4 v = *(const float4*)(xr + tid * 4);
  float s  = v.x + v.y + v.z + v.w;
  float sq = v.x*v.x + v.y*v.y + v.z*v.z + v.w*v.w;
  #pragma unroll
  for (int off = 32; off; off >>= 1){ s += __shfl_down(s, off); sq += __shfl_down(sq, off); }
  __shared__ float red[8];
  __shared__ float stats[2];
  int wid = tid >> 6;
  if ((tid & 63) == 0){ red[wid] = s; red[4 + wid] = sq; }
  __syncthreads();
  if (tid == 0){
    float S1 = red[0] + red[1] + red[2] + red[3];
    float S2 = red[4] + red[5] + red[6] + red[7];
    float mu = S1 * (1.0f / D_);
    float var = S2 * (1.0f / D_) - mu * mu;
    stats[0] = mu; stats[1] = rsqrtf(var + eps);
  }
  __syncthreads();
  float mu = stats[0], rs = stats[1];
  int i = tid * 4;
  float4 wv = *(const float4*)(w + i);
  float4 bv = *(const float4*)(b + i);
  float4 o;
  o.x = (v.x - mu) * rs * wv.x + bv.x;
  o.y = (v.y - mu) * rs * wv.y + bv.y;
  o.z = (v.z - mu) * rs * wv.z + bv.z;
  o.w = (v.w - mu) * rs * wv.w + bv.w;
  *(float4*)(outp + (size_t)row * D_ + i) = o;
}

// ---- C = silu(A @ B): A fp32 MxK row-major, B fp32 KxN row-major ----
// M=4096 N=2048 K=1024, 64x64 tile, 256 thr, 4x4 per thread, K-step 16
__global__ __launch_bounds__(256) void gemm_silu_kernel(const float* __restrict__ A,
    const float* __restrict__ Bm, float* __restrict__ C){
  const int N = P_, K = D_;
  __shared__ float As[16][65];
  __shared__ float Bs[16][64];
  int tid = threadIdx.x;
  int m0 = blockIdx.y * 64, n0 = blockIdx.x * 64;
  int ty = tid >> 4, tx = tid & 15;
  int am = tid >> 2, ak = (tid & 3) * 4;
  int bk = tid >> 4, bn = (tid & 15) * 4;
  float acc[4][4] = {};
  const float* Ap = A + (size_t)(m0 + am) * K + ak;
  const float* Bp = Bm + (size_t)bk * N + n0 + bn;
  for (int k0 = 0; k0 < K; k0 += 16){
    float4 av = *(const float4*)(Ap + k0);
    float4 bv = *(const float4*)(Bp + (size_t)k0 * N);
    As[ak+0][am] = av.x; As[ak+1][am] = av.y; As[ak+2][am] = av.z; As[ak+3][am] = av.w;
    Bs[bk][bn+0] = bv.x; Bs[bk][bn+1] = bv.y; Bs[bk][bn+2] = bv.z; Bs[bk][bn+3] = bv.w;
    __syncthreads();
    #pragma unroll
    for (int kk = 0; kk < 16; kk++){
      float a0 = As[kk][ty*4+0], a1 = As[kk][ty*4+1], a2 = As[kk][ty*4+2], a3 = As[kk][ty*4+3];
      float b0 = Bs[kk][tx*4+0], b1 = Bs[kk][tx*4+1], b2 = Bs[kk][tx*4+2], b3 = Bs[kk][tx*4+3];
      acc[0][0] += a0*b0; acc[0][1] += a0*b1; acc[0][2] += a0*b2; acc[0][3] += a0*b3;
      acc[1][0] += a1*b0; acc[1][1] += a1*b1; acc[1][2] += a1*b2; acc[1][3] += a1*b3;
      acc[2][0] += a2*b0; acc[2][1] += a2*b1; acc[2][2] += a2*b2; acc[2][3] += a2*b3;
      acc[3][0] += a3*b0; acc[3][1] += a3*b1; acc[3][2] += a3*b2; acc[3][3] += a3*b3;
    }
    __syncthreads();
  }
  #pragma unroll
  for (int i = 0; i < 4; i++){
    float4 o;
    o.x = silu(acc[i][0]); o.y = silu(acc[i][1]); o.z = silu(acc[i][2]); o.w = silu(acc[i][3]);
    *(float4*)(C + (size_t)(m0 + ty*4 + i) * N + n0 + tx*4) = o;
  }
}

// ---- causal silu-attention + no-affine norm + u-gate -> udot (B,S,F) ----
__global__ __launch_bounds__(256) void attn_kernel(const float* __restrict__ proj,
                                                   float* __restrict__ udot){
  __shared__ float qs[32][65];
  __shared__ float ks[64][65];
  __shared__ float vs[64][64];
  __shared__ float sc[32][65];
  __shared__ float smu[32], srs[32];
  int bx = blockIdx.x;          // s-tile (32 rows)
  int bh = blockIdx.y;          // b*H + h
  int b = bh >> 3, hh = bh & 7;
  int tid = threadIdx.x;
  int ty = tid >> 4, tx = tid & 15;
  int wid = tid >> 6, lane = tid & 63;
  int s0 = bx * 32;
  const size_t prow = ((size_t)b * S_ + s0) * P_;
  const int uoff = hh * 64;
  const int voff = F_ + hh * 64;
  const int qoff = 2 * F_ + hh * 64;
  const int koff = 3 * F_ + hh * 64;
  #pragma unroll
  for (int kq = 0; kq < 8; kq++){
    int r = kq * 4 + wid;
    qs[r][lane] = proj[prow + (size_t)r * P_ + qoff + lane];
  }
  float oacc[2][4] = {};
  int ntile = (s0 >> 6) + 1;
  for (int t = 0; t < ntile; t++){
    int t0 = t * 64;
    const size_t krow = ((size_t)b * S_ + t0) * P_;
    __syncthreads();   // protect ks/vs (and qs on iter 0)
    #pragma unroll
    for (int kq = 0; kq < 16; kq++){
      int r = kq * 4 + wid;
      ks[r][lane] = proj[krow + (size_t)r * P_ + koff + lane];
      vs[r][lane] = proj[krow + (size_t)r * P_ + voff + lane];
    }
    __syncthreads();
    float sacc[2][4] = {};
    #pragma unroll
    for (int d = 0; d < 64; d++){
      float a0 = qs[ty*2+0][d], a1 = qs[ty*2+1][d];
      float b0 = ks[tx*4+0][d], b1 = ks[tx*4+1][d], b2 = ks[tx*4+2][d], b3 = ks[tx*4+3][d];
      sacc[0][0] += a0*b0; sacc[0][1] += a0*b1; sacc[0][2] += a0*b2; sacc[0][3] += a0*b3;
      sacc[1][0] += a1*b0; sacc[1][1] += a1*b1; sacc[1][2] += a1*b2; sacc[1][3] += a1*b3;
    }
    #pragma unroll
    for (int i = 0; i < 2; i++){
      #pragma unroll
      for (int j = 0; j < 4; j++){
        int srow = s0 + ty*2 + i;
        int tcol = t0 + tx*4 + j;
        float v = sacc[i][j];
        sc[ty*2+i][tx*4+j] = (tcol <= srow) ? silu(v) * (1.0f / S_) : 0.0f;
      }
    }
    __syncthreads();
    #pragma unroll
    for (int tt = 0; tt < 64; tt++){
      float p0 = sc[ty*2+0][tt], p1 = sc[ty*2+1][tt];
      float v0 = vs[tt][tx*4+0], v1 = vs[tt][tx*4+1], v2 = vs[tt][tx*4+2], v3 = vs[tt][tx*4+3];
      oacc[0][0] += p0*v0; oacc[0][1] += p0*v1; oacc[0][2] += p0*v2; oacc[0][3] += p0*v3;
      oacc[1][0] += p1*v0; oacc[1][1] += p1*v1; oacc[1][2] += p1*v2; oacc[1][3] += p1*v3;
    }
  }
  __syncthreads();  // protect sc reuse against last out-phase reads
  #pragma unroll
  for (int i = 0; i < 2; i++)
    #pragma unroll
    for (int j = 0; j < 4; j++)
      sc[ty*2+i][tx*4+j] = oacc[i][j];
  __syncthreads();
  if (tid < 32){
    float s = 0.f, sq = 0.f;
    for (int c = 0; c < 64; c++){ float v = sc[tid][c]; s += v; sq += v*v; }
    float mu = s * (1.0f / 64.0f);
    float var = sq * (1.0f / 64.0f) - mu * mu;
    smu[tid] = mu; srs[tid] = rsqrtf(var + 1e-6f);
  }
  __syncthreads();
  #pragma unroll
  for (int i = 0; i < 2; i++){
    int r = ty*2 + i;
    float mu = smu[r], rs = srs[r];
    float4 uu = *(const float4*)(proj + prow + (size_t)r * P_ + uoff + tx*4);
    float4 o;
    o.x = (oacc[i][0] - mu) * rs * uu.x;
    o.y = (oacc[i][1] - mu) * rs * uu.y;
    o.z = (oacc[i][2] - mu) * rs * uu.z;
    o.w = (oacc[i][3] - mu) * rs * uu.w;
    *(float4*)(udot + ((size_t)b * S_ + s0 + r) * F_ + hh*64 + tx*4) = o;
  }
}

// ---- X[r,d] += sum_f A[r,f] * W[d,f] + bias[d]  (W fp32 (D,F) row-major) ----
// M=4096 N=1024 K=512
__global__ __launch_bounds__(256) void gemm_add_kernel(const float* __restrict__ A,
    const float* __restrict__ W, const float* __restrict__ bias, float* __restrict__ X){
  const int N = D_, K = F_;
  __shared__ float As[16][65];
  __shared__ float Ws[16][65];
  int tid = threadIdx.x;
  int m0 = blockIdx.y * 64, n0 = blockIdx.x * 64;
  int ty = tid >> 4, tx = tid & 15;
  int am = tid >> 2, ak = (tid & 3) * 4;
  float acc[4][4] = {};
  for (int k0 = 0; k0 < K; k0 += 16){
    float4 av = *(const float4*)(A + (size_t)(m0 + am) * K + k0 + ak);
    float4 wv = *(const float4*)(W + (size_t)(n0 + am) * K + k0 + ak);
    As[ak+0][am] = av.x; As[ak+1][am] = av.y; As[ak+2][am] = av.z; As[ak+3][am] = av.w;
    Ws[ak+0][am] = wv.x; Ws[ak+1][am] = wv.y; Ws[ak+2][am] = wv.z; Ws[ak+3][am] = wv.w;
    __syncthreads();
    #pragma unroll
    for (int kk = 0; kk < 16; kk++){
      float a0 = As[kk][ty*4+0], a1 = As[kk][ty*4+1], a2 = As[kk][ty*4+2], a3 = As[kk][ty*4+3];
      float b0 = Ws[kk][tx*4+0], b1 = Ws[kk][tx*4+1], b2 = Ws[kk][tx*4+2], b3 = Ws[kk][tx*4+3];
      acc[0][0] += a0*b0; acc[0][1] += a0*b1; acc[0][2] += a0*b2; acc[0][3] += a0*b3;
      acc[1][0] += a1*b0; acc[1][1] += a1*b1; acc[1][2] += a1*b2; acc[1][3] += a1*b3;
      acc[2][0] += a2*b0; acc[2][1] += a2*b1; acc[2][2] += a2*b2; acc[2][3] += a2*b3;
      acc[3][0] += a3*b0; acc[3][1] += a3*b1; acc[3][2] += a3*b2; acc[3][3] += a3*b3;
    }
    __syncthreads();
  }
  float4 bb = *(const float4*)(bias + n0 + tx*4);
  float bias4[4] = { bb.x, bb.y, bb.z, bb.w };
  #pragma unroll
  for (int i = 0; i < 4; i++){
    size_t off = (size_t)(m0 + ty*4 + i) * N + n0 + tx*4;
    float4 xv = *(const float4*)(X + off);
    float4 o;
    o.x = xv.x + acc[i][0] + bias4[0];
    o.y = xv.y + acc[i][1] + bias4[1];
    o.z = xv.z + acc[i][2] + bias4[2];
    o.w = xv.w + acc[i][3] + bias4[3];
    *(float4*)(X + off) = o;
  }
}

extern "C" void kernel_launch(void* const* d_in, const int* in_sizes, int n_in,
                              void* d_out, int out_size, void* d_ws, size_t ws_size,
                              hipStream_t stream){
  (void)in_sizes; (void)n_in; (void)out_size; (void)ws_size;
  const float* x     = (const float*)d_in[0];
  // d_in[1] = attn_mask (deterministic causal tril) -- unused
  const float* uvqk  = (const float*)d_in[2];
  const float* o_w   = (const float*)d_in[3];
  const float* o_b   = (const float*)d_in[4];
  const float* ln_w  = (const float*)d_in[5];
  const float* ln_b  = (const float*)d_in[6];
  const float* lln_w = (const float*)d_in[7];
  const float* lln_b = (const float*)d_in[8];
  float* out = (float*)d_out;

  float* xf   = (float*)d_ws;                 // 4096x1024
  float* h    = xf + (size_t)R_ * D_;         // 4096x1024 (reused as udot)
  float* proj = h + (size_t)R_ * D_;          // 4096x2048
  float* udot = h;                            // alias: h dead after gemm_silu

  cvt_kernel<<<R_ * D_ / 1024, 256, 0, stream>>>(x, xf);
  for (int l = 0; l < L_; l++){
    ln_kernel<<<R_, 256, 0, stream>>>(xf, ln_w + l * D_, ln_b + l * D_, h, 1e-6f);
    gemm_silu_kernel<<<dim3(P_ / 64, R_ / 64), 256, 0, stream>>>(
        h, uvqk + (size_t)l * D_ * P_, proj);
    attn_kernel<<<dim3(S_ / 32, B_ * H_), 256, 0, stream>>>(proj, udot);
    gemm_add_kernel<<<dim3(D_ / 64, R_ / 64), 256, 0, stream>>>(
        udot, o_w + (size_t)l * D_ * F_, o_b + l * D_, xf);
  }
  ln_kernel<<<R_, 256, 0, stream>>>(xf, lln_w, lln_b, out, 1e-8f);
}

// Round 3
// 926.123 us; speedup vs baseline: 2.2986x; 2.2986x over previous
//
#include <hip/hip_runtime.h>

// HSTU block, B=2 S=2048 D=1024 H=8 head=64 L=2. Inputs/outputs fp32.
// ws (48 MB): xf fp32(16M) | h/udot fp32(16M) | projh bf16(16M).
#define B_ 2
#define S_ 2048
#define D_ 1024
#define H_ 8
#define L_ 2
#define P_ 2048   // proj dim
#define F_ 512    // DL*H
#define R_ (B_*S_)

typedef unsigned short u16;
typedef unsigned int u32;
typedef __bf16 bf16;
typedef bf16 bf16x8 __attribute__((ext_vector_type(8)));
typedef short short8 __attribute__((ext_vector_type(8)));
typedef float v4f __attribute__((ext_vector_type(4)));

__device__ __forceinline__ float silu(float x){ return x / (1.0f + __expf(-x)); }
__device__ __forceinline__ float bf2f(u16 u){
  union { u32 i; float f; } x; x.i = ((u32)u) << 16; return x.f;
}
__device__ __forceinline__ u16 f2bfu(float f){
  union { float f; u32 i; } x; x.f = f;
  u32 r = x.i + 0x7fff + ((x.i >> 16) & 1);   // RNE
  return (u16)(r >> 16);
}

// ---- x copy ----
__global__ __launch_bounds__(256) void cvt_kernel(const float* __restrict__ x, float* __restrict__ xf){
  int i = (blockIdx.x * 256 + threadIdx.x) * 4;
  *(float4*)(xf + i) = *(const float4*)(x + i);
}

// ---- LayerNorm over D=1024; one block per row; fp32 out ----
__global__ __launch_bounds__(256) void ln_kernel(const float* __restrict__ xf,
    const float* __restrict__ w, const float* __restrict__ b,
    float* __restrict__ outp, float eps){
  int row = blockIdx.x, tid = threadIdx.x;
  const float* xr = xf + (size_t)row * D_;
  float4 v = *(const float4*)(xr + tid * 4);
  float s  = v.x + v.y + v.z + v.w;
  float sq = v.x*v.x + v.y*v.y + v.z*v.z + v.w*v.w;
  #pragma unroll
  for (int off = 32; off; off >>= 1){ s += __shfl_down(s, off); sq += __shfl_down(sq, off); }
  __shared__ float red[8];
  __shared__ float stats[2];
  int wid = tid >> 6;
  if ((tid & 63) == 0){ red[wid] = s; red[4 + wid] = sq; }
  __syncthreads();
  if (tid == 0){
    float S1 = red[0] + red[1] + red[2] + red[3];
    float S2 = red[4] + red[5] + red[6] + red[7];
    float mu = S1 * (1.0f / D_);
    float var = S2 * (1.0f / D_) - mu * mu;
    stats[0] = mu; stats[1] = rsqrtf(var + eps);
  }
  __syncthreads();
  float mu = stats[0], rs = stats[1];
  int i = tid * 4;
  float4 wv = *(const float4*)(w + i);
  float4 bv = *(const float4*)(b + i);
  float4 o;
  o.x = (v.x - mu) * rs * wv.x + bv.x;
  o.y = (v.y - mu) * rs * wv.y + bv.y;
  o.z = (v.z - mu) * rs * wv.z + bv.z;
  o.w = (v.w - mu) * rs * wv.w + bv.w;
  *(float4*)(outp + (size_t)row * D_ + i) = o;
}

// ---- proj = silu(A @ B) -> bf16: A fp32 MxK, B fp32 KxN row-major ----
__global__ __launch_bounds__(256) void gemm_silu_kernel(const float* __restrict__ A,
    const float* __restrict__ Bm, u16* __restrict__ C){
  const int N = P_, K = D_;
  __shared__ float As[16][65];
  __shared__ float Bs[16][64];
  int tid = threadIdx.x;
  int m0 = blockIdx.y * 64, n0 = blockIdx.x * 64;
  int ty = tid >> 4, tx = tid & 15;
  int am = tid >> 2, ak = (tid & 3) * 4;
  int bk = tid >> 4, bn = (tid & 15) * 4;
  float acc[4][4] = {};
  const float* Ap = A + (size_t)(m0 + am) * K + ak;
  const float* Bp = Bm + (size_t)bk * N + n0 + bn;
  for (int k0 = 0; k0 < K; k0 += 16){
    float4 av = *(const float4*)(Ap + k0);
    float4 bv = *(const float4*)(Bp + (size_t)k0 * N);
    As[ak+0][am] = av.x; As[ak+1][am] = av.y; As[ak+2][am] = av.z; As[ak+3][am] = av.w;
    Bs[bk][bn+0] = bv.x; Bs[bk][bn+1] = bv.y; Bs[bk][bn+2] = bv.z; Bs[bk][bn+3] = bv.w;
    __syncthreads();
    #pragma unroll
    for (int kk = 0; kk < 16; kk++){
      float a0 = As[kk][ty*4+0], a1 = As[kk][ty*4+1], a2 = As[kk][ty*4+2], a3 = As[kk][ty*4+3];
      float b0 = Bs[kk][tx*4+0], b1 = Bs[kk][tx*4+1], b2 = Bs[kk][tx*4+2], b3 = Bs[kk][tx*4+3];
      acc[0][0] += a0*b0; acc[0][1] += a0*b1; acc[0][2] += a0*b2; acc[0][3] += a0*b3;
      acc[1][0] += a1*b0; acc[1][1] += a1*b1; acc[1][2] += a1*b2; acc[1][3] += a1*b3;
      acc[2][0] += a2*b0; acc[2][1] += a2*b1; acc[2][2] += a2*b2; acc[2][3] += a2*b3;
      acc[3][0] += a3*b0; acc[3][1] += a3*b1; acc[3][2] += a3*b2; acc[3][3] += a3*b3;
    }
    __syncthreads();
  }
  #pragma unroll
  for (int i = 0; i < 4; i++){
    ushort4 o;
    o.x = f2bfu(silu(acc[i][0])); o.y = f2bfu(silu(acc[i][1]));
    o.z = f2bfu(silu(acc[i][2])); o.w = f2bfu(silu(acc[i][3]));
    *(ushort4*)(C + (size_t)(m0 + ty*4 + i) * N + n0 + tx*4) = o;
  }
}

// ---- MFMA bf16 causal silu-attention + 64-dim norm + u-gate -> udot fp32 ----
// grid (32, B*H), 256 thr (4 waves). Block: 64 q-rows (wave w: 16 rows),
// loop 64-row k/v tiles. qt remapped heavy-first for load balance.
__global__ __launch_bounds__(256) void attn_kernel(const u16* __restrict__ projh,
                                                   float* __restrict__ udot){
  __shared__ u16  ks[64*72];     // [krow][d] bf16, stride 72 (bank-spread, 16B-aligned rows)
  __shared__ u32  vs[64*36];     // [dv][t/2] packed bf16 pairs, stride 36 words
  __shared__ float Ps[64*68];    // [m][t] fp32, stride 68
  int qt = 31 - (int)blockIdx.x;            // heavy tiles first
  int bh = blockIdx.y;
  int b = bh >> 3, hh = bh & 7;
  int tid = threadIdx.x;
  int w = tid >> 6, lane = tid & 63, quad = lane >> 4, l15 = lane & 15;
  int s0 = qt * 64;
  const size_t bS = (size_t)b * S_;
  const int uoff = hh*64, voff = F_ + hh*64, qoff = 2*F_ + hh*64, koff = 3*F_ + hh*64;

  // q A-frags (A[m=lane&15][k=quad*8+j]), resident across all tiles
  bf16x8 aq0, aq1;
  {
    const u16* qp = projh + (bS + s0 + w*16 + l15) * P_ + qoff + quad*8;
    aq0 = __builtin_bit_cast(bf16x8, *(const short8*)qp);
    aq1 = __builtin_bit_cast(bf16x8, *(const short8*)(qp + 32));
  }

  v4f oacc[4];
  #pragma unroll
  for (int i = 0; i < 4; i++) oacc[i] = (v4f){0.f, 0.f, 0.f, 0.f};

  const int krow = tid >> 2, kd0 = (tid & 3) * 16;       // ks staging map
  const int vr0 = (tid & 31) * 2, vc0 = (tid >> 5) * 8;  // vs staging map

  for (int t = 0; t <= qt; t++){
    int t0 = t * 64;
    __syncthreads();   // prior iter's frag reads done before restage
    { // stage k-tile (row-major, padded)
      const u16* kp = projh + (bS + t0 + krow) * P_ + koff + kd0;
      short8 k0 = *(const short8*)kp;
      short8 k1 = *(const short8*)(kp + 8);
      *(short8*)&ks[krow*72 + kd0]     = k0;
      *(short8*)&ks[krow*72 + kd0 + 8] = k1;
    }
    { // stage v-tile transposed + pair-packed: vs[dv][t/2]
      const u16* vp = projh + (bS + t0 + vr0) * P_ + voff + vc0;
      short8 va = *(const short8*)vp;
      short8 vb = *(const short8*)(vp + P_);
      #pragma unroll
      for (int i = 0; i < 8; i++){
        u32 pk = (u32)(u16)va[i] | ((u32)(u16)vb[i] << 16);
        vs[(vc0 + i)*36 + (vr0 >> 1)] = pk;
      }
    }
    __syncthreads();

    // QK^T: S[16 x 64] per wave, K=64 head dim (2 mfma k-steps)
    v4f sacc[4];
    #pragma unroll
    for (int i = 0; i < 4; i++) sacc[i] = (v4f){0.f, 0.f, 0.f, 0.f};
    #pragma unroll
    for (int ns = 0; ns < 4; ns++){
      bf16x8 bk0 = __builtin_bit_cast(bf16x8, *(const short8*)&ks[(ns*16 + l15)*72 + quad*8]);
      bf16x8 bk1 = __builtin_bit_cast(bf16x8, *(const short8*)&ks[(ns*16 + l15)*72 + 32 + quad*8]);
      sacc[ns] = __builtin_amdgcn_mfma_f32_16x16x32_bf16(aq0, bk0, sacc[ns], 0, 0, 0);
      sacc[ns] = __builtin_amdgcn_mfma_f32_16x16x32_bf16(aq1, bk1, sacc[ns], 0, 0, 0);
    }

    // mask + silu/S; C layout: row=quad*4+r, col=l15 -> Ps[m][t] fp32
    bool diag = (t == qt);
    #pragma unroll
    for (int ns = 0; ns < 4; ns++){
      #pragma unroll
      for (int r = 0; r < 4; r++){
        int rl = w*16 + quad*4 + r;
        int cl = ns*16 + l15;
        float p = silu(sacc[ns][r]) * (1.0f / S_);
        if (diag && cl > rl) p = 0.0f;
        Ps[rl*68 + cl] = p;
      }
    }
    // PV: O[16 x 64] += P[16 x 64] @ V[64 x 64]  (wave-private Ps rows)
    #pragma unroll
    for (int kst = 0; kst < 2; kst++){
      const float* pp = &Ps[(w*16 + l15)*68 + kst*32 + quad*8];
      v4f p0 = *(const v4f*)pp;
      v4f p1 = *(const v4f*)(pp + 4);
      short8 aps;
      aps[0]=(short)f2bfu(p0[0]); aps[1]=(short)f2bfu(p0[1]);
      aps[2]=(short)f2bfu(p0[2]); aps[3]=(short)f2bfu(p0[3]);
      aps[4]=(short)f2bfu(p1[0]); aps[5]=(short)f2bfu(p1[1]);
      aps[6]=(short)f2bfu(p1[2]); aps[7]=(short)f2bfu(p1[3]);
      bf16x8 ap = __builtin_bit_cast(bf16x8, aps);
      #pragma unroll
      for (int ds = 0; ds < 4; ds++){
        bf16x8 bv = __builtin_bit_cast(bf16x8, *(const short8*)&vs[(ds*16 + l15)*36 + kst*16 + quad*4]);
        oacc[ds] = __builtin_amdgcn_mfma_f32_16x16x32_bf16(ap, bv, oacc[ds], 0, 0, 0);
      }
    }
  }

  // epilogue: per-row (64-wide) mean/var across the quad's 16 lanes, gate by u
  #pragma unroll
  for (int r = 0; r < 4; r++){
    float s  = oacc[0][r] + oacc[1][r] + oacc[2][r] + oacc[3][r];
    float sq = oacc[0][r]*oacc[0][r] + oacc[1][r]*oacc[1][r]
             + oacc[2][r]*oacc[2][r] + oacc[3][r]*oacc[3][r];
    #pragma unroll
    for (int m = 1; m < 16; m <<= 1){
      s  += __shfl_xor(s, m, 64);
      sq += __shfl_xor(sq, m, 64);
    }
    float mu = s * (1.0f/64.0f);
    float var = sq * (1.0f/64.0f) - mu*mu;
    float rs = rsqrtf(var + 1e-6f);
    int sg = s0 + w*16 + quad*4 + r;
    const u16* up = projh + (bS + sg) * P_ + uoff + l15;
    float* op = udot + (bS + sg) * (size_t)F_ + hh*64 + l15;
    #pragma unroll
    for (int ds = 0; ds < 4; ds++){
      float uu = bf2f(up[ds*16]);
      op[ds*16] = (oacc[ds][r] - mu) * rs * uu;
    }
  }
}

// ---- X[r,d] += sum_f A[r,f] * W[d,f] + bias[d]  (all fp32) ----
__global__ __launch_bounds__(256) void gemm_add_kernel(const float* __restrict__ A,
    const float* __restrict__ W, const float* __restrict__ bias, float* __restrict__ X){
  const int N = D_, K = F_;
  __shared__ float As[16][65];
  __shared__ float Ws[16][65];
  int tid = threadIdx.x;
  int m0 = blockIdx.y * 64, n0 = blockIdx.x * 64;
  int ty = tid >> 4, tx = tid & 15;
  int am = tid >> 2, ak = (tid & 3) * 4;
  float acc[4][4] = {};
  for (int k0 = 0; k0 < K; k0 += 16){
    float4 av = *(const float4*)(A + (size_t)(m0 + am) * K + k0 + ak);
    float4 wv = *(const float4*)(W + (size_t)(n0 + am) * K + k0 + ak);
    As[ak+0][am] = av.x; As[ak+1][am] = av.y; As[ak+2][am] = av.z; As[ak+3][am] = av.w;
    Ws[ak+0][am] = wv.x; Ws[ak+1][am] = wv.y; Ws[ak+2][am] = wv.z; Ws[ak+3][am] = wv.w;
    __syncthreads();
    #pragma unroll
    for (int kk = 0; kk < 16; kk++){
      float a0 = As[kk][ty*4+0], a1 = As[kk][ty*4+1], a2 = As[kk][ty*4+2], a3 = As[kk][ty*4+3];
      float b0 = Ws[kk][tx*4+0], b1 = Ws[kk][tx*4+1], b2 = Ws[kk][tx*4+2], b3 = Ws[kk][tx*4+3];
      acc[0][0] += a0*b0; acc[0][1] += a0*b1; acc[0][2] += a0*b2; acc[0][3] += a0*b3;
      acc[1][0] += a1*b0; acc[1][1] += a1*b1; acc[1][2] += a1*b2; acc[1][3] += a1*b3;
      acc[2][0] += a2*b0; acc[2][1] += a2*b1; acc[2][2] += a2*b2; acc[2][3] += a2*b3;
      acc[3][0] += a3*b0; acc[3][1] += a3*b1; acc[3][2] += a3*b2; acc[3][3] += a3*b3;
    }
    __syncthreads();
  }
  float4 bb = *(const float4*)(bias + n0 + tx*4);
  #pragma unroll
  for (int i = 0; i < 4; i++){
    size_t off = (size_t)(m0 + ty*4 + i) * N + n0 + tx*4;
    float4 xv = *(const float4*)(X + off);
    float4 o;
    o.x = xv.x + acc[i][0] + bb.x;
    o.y = xv.y + acc[i][1] + bb.y;
    o.z = xv.z + acc[i][2] + bb.z;
    o.w = xv.w + acc[i][3] + bb.w;
    *(float4*)(X + off) = o;
  }
}

extern "C" void kernel_launch(void* const* d_in, const int* in_sizes, int n_in,
                              void* d_out, int out_size, void* d_ws, size_t ws_size,
                              hipStream_t stream){
  (void)in_sizes; (void)n_in; (void)out_size; (void)ws_size;
  const float* x     = (const float*)d_in[0];
  // d_in[1] = attn_mask (causal tril) -- hardcoded
  const float* uvqk  = (const float*)d_in[2];
  const float* o_w   = (const float*)d_in[3];
  const float* o_b   = (const float*)d_in[4];
  const float* ln_w  = (const float*)d_in[5];
  const float* ln_b  = (const float*)d_in[6];
  const float* lln_w = (const float*)d_in[7];
  const float* lln_b = (const float*)d_in[8];
  float* out = (float*)d_out;

  float* xf    = (float*)d_ws;                 // 4096x1024 fp32
  float* h     = xf + (size_t)R_ * D_;         // 4096x1024 fp32 (reused as udot)
  u16*   projh = (u16*)(h + (size_t)R_ * D_);  // 4096x2048 bf16
  float* udot  = h;

  cvt_kernel<<<R_ * D_ / 1024, 256, 0, stream>>>(x, xf);
  for (int l = 0; l < L_; l++){
    ln_kernel<<<R_, 256, 0, stream>>>(xf, ln_w + l * D_, ln_b + l * D_, h, 1e-6f);
    gemm_silu_kernel<<<dim3(P_ / 64, R_ / 64), 256, 0, stream>>>(
        h, uvqk + (size_t)l * D_ * P_, projh);
    attn_kernel<<<dim3(S_ / 64, B_ * H_), 256, 0, stream>>>(projh, udot);
    gemm_add_kernel<<<dim3(D_ / 64, R_ / 64), 256, 0, stream>>>(
        udot, o_w + (size_t)l * D_ * F_, o_b + l * D_, xf);
  }
  ln_kernel<<<R_, 256, 0, stream>>>(xf, lln_w, lln_b, out, 1e-8f);
}

// Round 4
// 375.149 us; speedup vs baseline: 5.6745x; 2.4687x over previous
//
#include <hip/hip_runtime.h>

// HSTU block, B=2 S=2048 D=1024 H=8 head=64 L=2. Inputs/outputs fp32.
// ws (54 MB): xf f32(16M) | h bf16(8M) | udot bf16(4M) | projh bf16(16M)
//           | uvqkT bf16(8M) | owh bf16(2M)
#define B_ 2
#define S_ 2048
#define D_ 1024
#define H_ 8
#define L_ 2
#define P_ 2048   // proj dim
#define F_ 512    // DL*H
#define R_ (B_*S_)

typedef unsigned short u16;
typedef unsigned int u32;
typedef __bf16 bf16;
typedef bf16 bf16x8 __attribute__((ext_vector_type(8)));
typedef short short8 __attribute__((ext_vector_type(8)));
typedef float v4f __attribute__((ext_vector_type(4)));

__device__ __forceinline__ float silu(float x){ return x / (1.0f + __expf(-x)); }
__device__ __forceinline__ float bf2f(u16 u){
  union { u32 i; float f; } x; x.i = ((u32)u) << 16; return x.f;
}
__device__ __forceinline__ u16 f2bfu(float f){
  union { float f; u32 i; } x; x.f = f;
  u32 r = x.i + 0x7fff + ((x.i >> 16) & 1);   // RNE
  return (u16)(r >> 16);
}
__device__ __forceinline__ void gload16(const u16* g, u16* l){
  __builtin_amdgcn_global_load_lds(
      (const __attribute__((address_space(1))) void*)g,
      (__attribute__((address_space(3))) void*)l, 16, 0, 0);
}

// ---- x copy ----
__global__ __launch_bounds__(256) void cvt_kernel(const float* __restrict__ x, float* __restrict__ xf){
  int i = (blockIdx.x * 256 + threadIdx.x) * 4;
  *(float4*)(xf + i) = *(const float4*)(x + i);
}

// ---- fp32 -> bf16 elementwise (o_w) ----
__global__ __launch_bounds__(256) void cvt_bf16_kernel(const float* __restrict__ src, u16* __restrict__ dst){
  int i = (blockIdx.x * 256 + threadIdx.x) * 4;
  float4 v = *(const float4*)(src + i);
  ushort4 o; o.x = f2bfu(v.x); o.y = f2bfu(v.y); o.z = f2bfu(v.z); o.w = f2bfu(v.w);
  *(ushort4*)(dst + i) = o;
}

// ---- uvqk (L,D,P) f32 -> uvqkT (L,P,D) bf16 ----
__global__ __launch_bounds__(256) void cvt_uvqkT_kernel(const float* __restrict__ uvqk, u16* __restrict__ ot){
  __shared__ float t[32][33];
  int l = blockIdx.z;
  int p0 = blockIdx.x * 32, d0 = blockIdx.y * 32;
  int tx = threadIdx.x & 31, ty = threadIdx.x >> 5;   // ty: 8 rows/pass
  const float* src = uvqk + ((size_t)l * D_ + d0) * P_ + p0;
  #pragma unroll
  for (int s = 0; s < 4; s++)
    t[ty + s*8][tx] = src[(size_t)(ty + s*8) * P_ + tx];
  __syncthreads();
  u16* dst = ot + ((size_t)l * P_ + p0) * D_ + d0;
  #pragma unroll
  for (int s = 0; s < 4; s++)
    dst[(size_t)(ty + s*8) * D_ + tx] = f2bfu(t[tx][ty + s*8]);
}

// ---- LayerNorm over D=1024; one block per row; bf16 or fp32 out ----
__global__ __launch_bounds__(256) void ln_kernel(const float* __restrict__ xf,
    const float* __restrict__ w, const float* __restrict__ b,
    void* __restrict__ outp, float eps, int out_bf16){
  int row = blockIdx.x, tid = threadIdx.x;
  const float* xr = xf + (size_t)row * D_;
  float4 v = *(const float4*)(xr + tid * 4);
  float s  = v.x + v.y + v.z + v.w;
  float sq = v.x*v.x + v.y*v.y + v.z*v.z + v.w*v.w;
  #pragma unroll
  for (int off = 32; off; off >>= 1){ s += __shfl_down(s, off); sq += __shfl_down(sq, off); }
  __shared__ float red[8];
  __shared__ float stats[2];
  int wid = tid >> 6;
  if ((tid & 63) == 0){ red[wid] = s; red[4 + wid] = sq; }
  __syncthreads();
  if (tid == 0){
    float S1 = red[0] + red[1] + red[2] + red[3];
    float S2 = red[4] + red[5] + red[6] + red[7];
    float mu = S1 * (1.0f / D_);
    float var = S2 * (1.0f / D_) - mu * mu;
    stats[0] = mu; stats[1] = rsqrtf(var + eps);
  }
  __syncthreads();
  float mu = stats[0], rs = stats[1];
  int i = tid * 4;
  float4 wv = *(const float4*)(w + i);
  float4 bv = *(const float4*)(b + i);
  float o0 = (v.x - mu) * rs * wv.x + bv.x;
  float o1 = (v.y - mu) * rs * wv.y + bv.y;
  float o2 = (v.z - mu) * rs * wv.z + bv.z;
  float o3 = (v.w - mu) * rs * wv.w + bv.w;
  if (out_bf16){
    ushort4 o; o.x = f2bfu(o0); o.y = f2bfu(o1); o.z = f2bfu(o2); o.w = f2bfu(o3);
    *(ushort4*)((u16*)outp + (size_t)row * D_ + i) = o;
  } else {
    *(float4*)((float*)outp + (size_t)row * D_ + i) = make_float4(o0, o1, o2, o3);
  }
}

// ---- MFMA GEMM core: C(128x128) = A(128xK) @ Bt(128xK)^T, bf16 in, f32 acc ----
// 256 thr = 4 waves, wave (wm,wn) owns 64x64 = 4x4 MFMA tiles. BK=32.
template<int KDIM>
__device__ __forceinline__ void gemm_mfma_core(const u16* __restrict__ A,
    const u16* __restrict__ Bt, u16* As, u16* Bs, int m0, int n0, v4f acc[4][4]){
  int tid = threadIdx.x;
  int w = tid >> 6, lane = tid & 63;
  int wm = w >> 1, wn = w & 1, quad = lane >> 4, l15 = lane & 15;
  int srow = lane >> 2, skoct = (lane & 3) * 8;
  for (int kt = 0; kt < KDIM; kt += 32){
    __syncthreads();
    #pragma unroll
    for (int s = 0; s < 2; s++){
      int g = w * 2 + s;
      gload16(A  + (size_t)(m0 + g*16 + srow) * KDIM + kt + skoct, As + g*512);
      gload16(Bt + (size_t)(n0 + g*16 + srow) * KDIM + kt + skoct, Bs + g*512);
    }
    __syncthreads();
    short8 af[4], bfr[4];
    #pragma unroll
    for (int i = 0; i < 4; i++)
      af[i] = *(const short8*)&As[(wm*64 + i*16 + l15)*32 + quad*8];
    #pragma unroll
    for (int j = 0; j < 4; j++)
      bfr[j] = *(const short8*)&Bs[(wn*64 + j*16 + l15)*32 + quad*8];
    #pragma unroll
    for (int i = 0; i < 4; i++)
      #pragma unroll
      for (int j = 0; j < 4; j++)
        acc[i][j] = __builtin_amdgcn_mfma_f32_16x16x32_bf16(
            __builtin_bit_cast(bf16x8, af[i]), __builtin_bit_cast(bf16x8, bfr[j]),
            acc[i][j], 0, 0, 0);
  }
}

// ---- projh = silu(h @ uvqk) -> bf16 ----
__global__ __launch_bounds__(256) void gemm_silu_mfma(const u16* __restrict__ A,
    const u16* __restrict__ Bt, u16* __restrict__ C){
  __shared__ u16 As[128*32], Bs[128*32];
  v4f acc[4][4];
  #pragma unroll
  for (int i = 0; i < 4; i++)
    #pragma unroll
    for (int j = 0; j < 4; j++) acc[i][j] = (v4f){0.f,0.f,0.f,0.f};
  int m0 = blockIdx.y * 128, n0 = blockIdx.x * 128;
  gemm_mfma_core<D_>(A, Bt, As, Bs, m0, n0, acc);
  int tid = threadIdx.x, w = tid >> 6, lane = tid & 63;
  int wm = w >> 1, wn = w & 1, quad = lane >> 4, l15 = lane & 15;
  #pragma unroll
  for (int i = 0; i < 4; i++)
    #pragma unroll
    for (int r = 0; r < 4; r++){
      int m = m0 + wm*64 + i*16 + quad*4 + r;
      u16* cp = C + (size_t)m * P_ + n0 + wn*64 + l15;
      #pragma unroll
      for (int j = 0; j < 4; j++)
        cp[j*16] = f2bfu(silu(acc[i][j][r]));
    }
}

// ---- xf += udot @ owh^T + o_b ----
__global__ __launch_bounds__(256) void gemm_add_mfma(const u16* __restrict__ A,
    const u16* __restrict__ Bt, const float* __restrict__ bias, float* __restrict__ X){
  __shared__ u16 As[128*32], Bs[128*32];
  v4f acc[4][4];
  #pragma unroll
  for (int i = 0; i < 4; i++)
    #pragma unroll
    for (int j = 0; j < 4; j++) acc[i][j] = (v4f){0.f,0.f,0.f,0.f};
  int m0 = blockIdx.y * 128, n0 = blockIdx.x * 128;
  gemm_mfma_core<F_>(A, Bt, As, Bs, m0, n0, acc);
  int tid = threadIdx.x, w = tid >> 6, lane = tid & 63;
  int wm = w >> 1, wn = w & 1, quad = lane >> 4, l15 = lane & 15;
  float bj[4];
  #pragma unroll
  for (int j = 0; j < 4; j++) bj[j] = bias[n0 + wn*64 + j*16 + l15];
  #pragma unroll
  for (int i = 0; i < 4; i++)
    #pragma unroll
    for (int r = 0; r < 4; r++){
      int m = m0 + wm*64 + i*16 + quad*4 + r;
      float* xp = X + (size_t)m * D_ + n0 + wn*64 + l15;
      #pragma unroll
      for (int j = 0; j < 4; j++)
        xp[j*16] += acc[i][j][r] + bj[j];
    }
}

// ---- MFMA bf16 causal silu-attention + 64-dim norm + u-gate -> udot bf16 ----
__global__ __launch_bounds__(256) void attn_kernel(const u16* __restrict__ projh,
                                                   u16* __restrict__ udot){
  __shared__ u16  ks[64*72];
  __shared__ u32  vs[64*36];
  __shared__ float Ps[64*68];
  int qt = 31 - (int)blockIdx.x;            // heavy tiles first
  int bh = blockIdx.y;
  int b = bh >> 3, hh = bh & 7;
  int tid = threadIdx.x;
  int w = tid >> 6, lane = tid & 63, quad = lane >> 4, l15 = lane & 15;
  int s0 = qt * 64;
  const size_t bS = (size_t)b * S_;
  const int uoff = hh*64, voff = F_ + hh*64, qoff = 2*F_ + hh*64, koff = 3*F_ + hh*64;

  bf16x8 aq0, aq1;
  {
    const u16* qp = projh + (bS + s0 + w*16 + l15) * P_ + qoff + quad*8;
    aq0 = __builtin_bit_cast(bf16x8, *(const short8*)qp);
    aq1 = __builtin_bit_cast(bf16x8, *(const short8*)(qp + 32));
  }

  v4f oacc[4];
  #pragma unroll
  for (int i = 0; i < 4; i++) oacc[i] = (v4f){0.f, 0.f, 0.f, 0.f};

  const int krow = tid >> 2, kd0 = (tid & 3) * 16;
  const int vr0 = (tid & 31) * 2, vc0 = (tid >> 5) * 8;

  for (int t = 0; t <= qt; t++){
    int t0 = t * 64;
    __syncthreads();
    {
      const u16* kp = projh + (bS + t0 + krow) * P_ + koff + kd0;
      short8 k0 = *(const short8*)kp;
      short8 k1 = *(const short8*)(kp + 8);
      *(short8*)&ks[krow*72 + kd0]     = k0;
      *(short8*)&ks[krow*72 + kd0 + 8] = k1;
    }
    {
      const u16* vp = projh + (bS + t0 + vr0) * P_ + voff + vc0;
      short8 va = *(const short8*)vp;
      short8 vb = *(const short8*)(vp + P_);
      #pragma unroll
      for (int i = 0; i < 8; i++){
        u32 pk = (u32)(u16)va[i] | ((u32)(u16)vb[i] << 16);
        vs[(vc0 + i)*36 + (vr0 >> 1)] = pk;
      }
    }
    __syncthreads();

    v4f sacc[4];
    #pragma unroll
    for (int i = 0; i < 4; i++) sacc[i] = (v4f){0.f, 0.f, 0.f, 0.f};
    #pragma unroll
    for (int ns = 0; ns < 4; ns++){
      bf16x8 bk0 = __builtin_bit_cast(bf16x8, *(const short8*)&ks[(ns*16 + l15)*72 + quad*8]);
      bf16x8 bk1 = __builtin_bit_cast(bf16x8, *(const short8*)&ks[(ns*16 + l15)*72 + 32 + quad*8]);
      sacc[ns] = __builtin_amdgcn_mfma_f32_16x16x32_bf16(aq0, bk0, sacc[ns], 0, 0, 0);
      sacc[ns] = __builtin_amdgcn_mfma_f32_16x16x32_bf16(aq1, bk1, sacc[ns], 0, 0, 0);
    }

    bool diag = (t == qt);
    #pragma unroll
    for (int ns = 0; ns < 4; ns++){
      #pragma unroll
      for (int r = 0; r < 4; r++){
        int rl = w*16 + quad*4 + r;
        int cl = ns*16 + l15;
        float p = silu(sacc[ns][r]) * (1.0f / S_);
        if (diag && cl > rl) p = 0.0f;
        Ps[rl*68 + cl] = p;
      }
    }
    #pragma unroll
    for (int kst = 0; kst < 2; kst++){
      const float* pp = &Ps[(w*16 + l15)*68 + kst*32 + quad*8];
      v4f p0 = *(const v4f*)pp;
      v4f p1 = *(const v4f*)(pp + 4);
      short8 aps;
      aps[0]=(short)f2bfu(p0[0]); aps[1]=(short)f2bfu(p0[1]);
      aps[2]=(short)f2bfu(p0[2]); aps[3]=(short)f2bfu(p0[3]);
      aps[4]=(short)f2bfu(p1[0]); aps[5]=(short)f2bfu(p1[1]);
      aps[6]=(short)f2bfu(p1[2]); aps[7]=(short)f2bfu(p1[3]);
      bf16x8 ap = __builtin_bit_cast(bf16x8, aps);
      #pragma unroll
      for (int ds = 0; ds < 4; ds++){
        bf16x8 bv = __builtin_bit_cast(bf16x8, *(const short8*)&vs[(ds*16 + l15)*36 + kst*16 + quad*4]);
        oacc[ds] = __builtin_amdgcn_mfma_f32_16x16x32_bf16(ap, bv, oacc[ds], 0, 0, 0);
      }
    }
  }

  #pragma unroll
  for (int r = 0; r < 4; r++){
    float s  = oacc[0][r] + oacc[1][r] + oacc[2][r] + oacc[3][r];
    float sq = oacc[0][r]*oacc[0][r] + oacc[1][r]*oacc[1][r]
             + oacc[2][r]*oacc[2][r] + oacc[3][r]*oacc[3][r];
    #pragma unroll
    for (int m = 1; m < 16; m <<= 1){
      s  += __shfl_xor(s, m, 64);
      sq += __shfl_xor(sq, m, 64);
    }
    float mu = s * (1.0f/64.0f);
    float var = sq * (1.0f/64.0f) - mu*mu;
    float rs = rsqrtf(var + 1e-6f);
    int sg = s0 + w*16 + quad*4 + r;
    const u16* up = projh + (bS + sg) * P_ + uoff + l15;
    u16* op = udot + (bS + sg) * (size_t)F_ + hh*64 + l15;
    #pragma unroll
    for (int ds = 0; ds < 4; ds++){
      float uu = bf2f(up[ds*16]);
      op[ds*16] = f2bfu((oacc[ds][r] - mu) * rs * uu);
    }
  }
}

extern "C" void kernel_launch(void* const* d_in, const int* in_sizes, int n_in,
                              void* d_out, int out_size, void* d_ws, size_t ws_size,
                              hipStream_t stream){
  (void)in_sizes; (void)n_in; (void)out_size; (void)ws_size;
  const float* x     = (const float*)d_in[0];
  // d_in[1] = attn_mask (causal tril) -- hardcoded
  const float* uvqk  = (const float*)d_in[2];
  const float* o_w   = (const float*)d_in[3];
  const float* o_b   = (const float*)d_in[4];
  const float* ln_w  = (const float*)d_in[5];
  const float* ln_b  = (const float*)d_in[6];
  const float* lln_w = (const float*)d_in[7];
  const float* lln_b = (const float*)d_in[8];
  float* out = (float*)d_out;

  char* ws = (char*)d_ws;
  float* xf    = (float*)ws;                          // 16 MB
  u16*   h     = (u16*)(ws + (16u<<20));              //  8 MB
  u16*   udot  = (u16*)(ws + (24u<<20));              //  4 MB
  u16*   projh = (u16*)(ws + (28u<<20));              // 16 MB
  u16*   uvqkT = (u16*)(ws + (44u<<20));              //  8 MB
  u16*   owh   = (u16*)(ws + (52u<<20));              //  2 MB

  cvt_kernel<<<R_ * D_ / 1024, 256, 0, stream>>>(x, xf);
  cvt_uvqkT_kernel<<<dim3(P_/32, D_/32, L_), 256, 0, stream>>>(uvqk, uvqkT);
  cvt_bf16_kernel<<<L_ * D_ * F_ / 1024, 256, 0, stream>>>(o_w, owh);
  for (int l = 0; l < L_; l++){
    ln_kernel<<<R_, 256, 0, stream>>>(xf, ln_w + l * D_, ln_b + l * D_, h, 1e-6f, 1);
    gemm_silu_mfma<<<dim3(P_/128, R_/128), 256, 0, stream>>>(
        h, uvqkT + (size_t)l * P_ * D_, projh);
    attn_kernel<<<dim3(S_/64, B_*H_), 256, 0, stream>>>(projh, udot);
    gemm_add_mfma<<<dim3(D_/128, R_/128), 256, 0, stream>>>(
        udot, owh + (size_t)l * D_ * F_, o_b + l * D_, xf);
  }
  ln_kernel<<<R_, 256, 0, stream>>>(xf, lln_w, lln_b, out, 1e-8f, 0);
}

// Round 7
// 345.733 us; speedup vs baseline: 6.1573x; 1.0851x over previous
//
#include <hip/hip_runtime.h>

// HSTU block, B=2 S=2048 D=1024 H=8 head=64 L=2. Inputs/outputs fp32.
// ws (62 MB): xf f32(16M) | h bf16(8M) | udot bf16(4M) | projh bf16(16M)
//           | uvqkT bf16(8M) | owh bf16(2M) | opart f32(8M)
#define B_ 2
#define S_ 2048
#define D_ 1024
#define H_ 8
#define L_ 2
#define P_ 2048   // proj dim
#define F_ 512    // DL*H
#define R_ (B_*S_)

typedef unsigned short u16;
typedef unsigned int u32;
typedef __bf16 bf16;
typedef bf16 bf16x8 __attribute__((ext_vector_type(8)));
typedef short short8 __attribute__((ext_vector_type(8)));
typedef float v4f __attribute__((ext_vector_type(4)));

__device__ __forceinline__ float silu(float x){ return x / (1.0f + __expf(-x)); }
__device__ __forceinline__ float bf2f(u16 u){
  union { u32 i; float f; } x; x.i = ((u32)u) << 16; return x.f;
}
__device__ __forceinline__ u16 f2bfu(float f){
  union { float f; u32 i; } x; x.f = f;
  u32 r = x.i + 0x7fff + ((x.i >> 16) & 1);   // RNE
  return (u16)(r >> 16);
}
__device__ __forceinline__ void gload16(const u16* g, u16* l){
  __builtin_amdgcn_global_load_lds(
      (const __attribute__((address_space(1))) void*)g,
      (__attribute__((address_space(3))) void*)l, 16, 0, 0);
}

// ---- x copy ----
__global__ __launch_bounds__(256) void cvt_kernel(const float* __restrict__ x, float* __restrict__ xf){
  int i = (blockIdx.x * 256 + threadIdx.x) * 4;
  *(float4*)(xf + i) = *(const float4*)(x + i);
}

// ---- zero fp32 buffer ----
__global__ __launch_bounds__(256) void zero_kernel(float* __restrict__ p){
  int i = (blockIdx.x * 256 + threadIdx.x) * 4;
  *(float4*)(p + i) = make_float4(0.f, 0.f, 0.f, 0.f);
}

// ---- fp32 -> bf16 elementwise (o_w) ----
__global__ __launch_bounds__(256) void cvt_bf16_kernel(const float* __restrict__ src, u16* __restrict__ dst){
  int i = (blockIdx.x * 256 + threadIdx.x) * 4;
  float4 v = *(const float4*)(src + i);
  ushort4 o; o.x = f2bfu(v.x); o.y = f2bfu(v.y); o.z = f2bfu(v.z); o.w = f2bfu(v.w);
  *(ushort4*)(dst + i) = o;
}

// ---- uvqk (L,D,P) f32 -> uvqkT (L,P,D) bf16 ----
__global__ __launch_bounds__(256) void cvt_uvqkT_kernel(const float* __restrict__ uvqk, u16* __restrict__ ot){
  __shared__ float t[32][33];
  int l = blockIdx.z;
  int p0 = blockIdx.x * 32, d0 = blockIdx.y * 32;
  int tx = threadIdx.x & 31, ty = threadIdx.x >> 5;   // ty: 8 rows/pass
  const float* src = uvqk + ((size_t)l * D_ + d0) * P_ + p0;
  #pragma unroll
  for (int s = 0; s < 4; s++)
    t[ty + s*8][tx] = src[(size_t)(ty + s*8) * P_ + tx];
  __syncthreads();
  u16* dst = ot + ((size_t)l * P_ + p0) * D_ + d0;
  #pragma unroll
  for (int s = 0; s < 4; s++)
    dst[(size_t)(ty + s*8) * D_ + tx] = f2bfu(t[tx][ty + s*8]);
}

// ---- LayerNorm over D=1024; one block per row; bf16 or fp32 out ----
__global__ __launch_bounds__(256) void ln_kernel(const float* __restrict__ xf,
    const float* __restrict__ w, const float* __restrict__ b,
    void* __restrict__ outp, float eps, int out_bf16){
  int row = blockIdx.x, tid = threadIdx.x;
  const float* xr = xf + (size_t)row * D_;
  float4 v = *(const float4*)(xr + tid * 4);
  float s  = v.x + v.y + v.z + v.w;
  float sq = v.x*v.x + v.y*v.y + v.z*v.z + v.w*v.w;
  #pragma unroll
  for (int off = 32; off; off >>= 1){ s += __shfl_down(s, off); sq += __shfl_down(sq, off); }
  __shared__ float red[8];
  __shared__ float stats[2];
  int wid = tid >> 6;
  if ((tid & 63) == 0){ red[wid] = s; red[4 + wid] = sq; }
  __syncthreads();
  if (tid == 0){
    float S1 = red[0] + red[1] + red[2] + red[3];
    float S2 = red[4] + red[5] + red[6] + red[7];
    float mu = S1 * (1.0f / D_);
    float var = S2 * (1.0f / D_) - mu * mu;
    stats[0] = mu; stats[1] = rsqrtf(var + eps);
  }
  __syncthreads();
  float mu = stats[0], rs = stats[1];
  int i = tid * 4;
  float4 wv = *(const float4*)(w + i);
  float4 bv = *(const float4*)(b + i);
  float o0 = (v.x - mu) * rs * wv.x + bv.x;
  float o1 = (v.y - mu) * rs * wv.y + bv.y;
  float o2 = (v.z - mu) * rs * wv.z + bv.z;
  float o3 = (v.w - mu) * rs * wv.w + bv.w;
  if (out_bf16){
    ushort4 o; o.x = f2bfu(o0); o.y = f2bfu(o1); o.z = f2bfu(o2); o.w = f2bfu(o3);
    *(ushort4*)((u16*)outp + (size_t)row * D_ + i) = o;
  } else {
    *(float4*)((float*)outp + (size_t)row * D_ + i) = make_float4(o0, o1, o2, o3);
  }
}

// ---- MFMA GEMM core: C(128x128) = A(128xK) @ Bt(128xK)^T, bf16 in, f32 acc ----
template<int KDIM>
__device__ __forceinline__ void gemm_mfma_core(const u16* __restrict__ A,
    const u16* __restrict__ Bt, u16* As, u16* Bs, int m0, int n0, v4f acc[4][4]){
  int tid = threadIdx.x;
  int w = tid >> 6, lane = tid & 63;
  int wm = w >> 1, wn = w & 1, quad = lane >> 4, l15 = lane & 15;
  int srow = lane >> 2, skoct = (lane & 3) * 8;
  for (int kt = 0; kt < KDIM; kt += 32){
    __syncthreads();
    #pragma unroll
    for (int s = 0; s < 2; s++){
      int g = w * 2 + s;
      gload16(A  + (size_t)(m0 + g*16 + srow) * KDIM + kt + skoct, As + g*512);
      gload16(Bt + (size_t)(n0 + g*16 + srow) * KDIM + kt + skoct, Bs + g*512);
    }
    __syncthreads();
    short8 af[4], bfr[4];
    #pragma unroll
    for (int i = 0; i < 4; i++)
      af[i] = *(const short8*)&As[(wm*64 + i*16 + l15)*32 + quad*8];
    #pragma unroll
    for (int j = 0; j < 4; j++)
      bfr[j] = *(const short8*)&Bs[(wn*64 + j*16 + l15)*32 + quad*8];
    #pragma unroll
    for (int i = 0; i < 4; i++)
      #pragma unroll
      for (int j = 0; j < 4; j++)
        acc[i][j] = __builtin_amdgcn_mfma_f32_16x16x32_bf16(
            __builtin_bit_cast(bf16x8, af[i]), __builtin_bit_cast(bf16x8, bfr[j]),
            acc[i][j], 0, 0, 0);
  }
}

// ---- projh = silu(h @ uvqk) -> bf16 ----
__global__ __launch_bounds__(256) void gemm_silu_mfma(const u16* __restrict__ A,
    const u16* __restrict__ Bt, u16* __restrict__ C){
  __shared__ u16 As[128*32], Bs[128*32];
  v4f acc[4][4];
  #pragma unroll
  for (int i = 0; i < 4; i++)
    #pragma unroll
    for (int j = 0; j < 4; j++) acc[i][j] = (v4f){0.f,0.f,0.f,0.f};
  int m0 = blockIdx.y * 128, n0 = blockIdx.x * 128;
  gemm_mfma_core<D_>(A, Bt, As, Bs, m0, n0, acc);
  int tid = threadIdx.x, w = tid >> 6, lane = tid & 63;
  int wm = w >> 1, wn = w & 1, quad = lane >> 4, l15 = lane & 15;
  #pragma unroll
  for (int i = 0; i < 4; i++)
    #pragma unroll
    for (int r = 0; r < 4; r++){
      int m = m0 + wm*64 + i*16 + quad*4 + r;
      u16* cp = C + (size_t)m * P_ + n0 + wn*64 + l15;
      #pragma unroll
      for (int j = 0; j < 4; j++)
        cp[j*16] = f2bfu(silu(acc[i][j][r]));
    }
}

// ---- xf += udot @ owh^T + o_b ----
__global__ __launch_bounds__(256) void gemm_add_mfma(const u16* __restrict__ A,
    const u16* __restrict__ Bt, const float* __restrict__ bias, float* __restrict__ X){
  __shared__ u16 As[128*32], Bs[128*32];
  v4f acc[4][4];
  #pragma unroll
  for (int i = 0; i < 4; i++)
    #pragma unroll
    for (int j = 0; j < 4; j++) acc[i][j] = (v4f){0.f,0.f,0.f,0.f};
  int m0 = blockIdx.y * 128, n0 = blockIdx.x * 128;
  gemm_mfma_core<F_>(A, Bt, As, Bs, m0, n0, acc);
  int tid = threadIdx.x, w = tid >> 6, lane = tid & 63;
  int wm = w >> 1, wn = w & 1, quad = lane >> 4, l15 = lane & 15;
  float bj[4];
  #pragma unroll
  for (int j = 0; j < 4; j++) bj[j] = bias[n0 + wn*64 + j*16 + l15];
  #pragma unroll
  for (int i = 0; i < 4; i++)
    #pragma unroll
    for (int r = 0; r < 4; r++){
      int m = m0 + wm*64 + i*16 + quad*4 + r;
      float* xp = X + (size_t)m * D_ + n0 + wn*64 + l15;
      #pragma unroll
      for (int j = 0; j < 4; j++)
        xp[j*16] += acc[i][j][r] + bj[j];
    }
}

// ---- MFMA bf16 causal silu-attention, kt-split partials -> opart fp32 ----
// ROUND-4-VERBATIM dataflow: grid (32, B*H, 4); 64-row q-tiles; 4 waves each
// own 16 q-rows x full 64 kt; diag-only local mask; Ps LDS round-trip.
// Only deltas vs round 4: t loop strides by 4 (z = blockIdx.z), epilogue
// atomicAdds raw O partials to opart (same validated address mapping).
__global__ __launch_bounds__(256) void attn_kernel(const u16* __restrict__ projh,
                                                   float* __restrict__ opart){
  __shared__ u16  ks[64*72];
  __shared__ u32  vs[64*36];
  __shared__ float Ps[64*68];
  int qt = 31 - (int)blockIdx.x;   // heavy tiles first
  int z  = blockIdx.z;             // kt-split 0..3
  int bh = blockIdx.y;
  int b = bh >> 3, hh = bh & 7;
  int tid = threadIdx.x;
  int w = tid >> 6, lane = tid & 63, quad = lane >> 4, l15 = lane & 15;
  int s0 = qt * 64;
  const size_t bS = (size_t)b * S_;
  const int voff = F_ + hh*64, qoff = 2*F_ + hh*64, koff = 3*F_ + hh*64;

  bf16x8 aq0, aq1;
  {
    const u16* qp = projh + (bS + s0 + w*16 + l15) * P_ + qoff + quad*8;
    aq0 = __builtin_bit_cast(bf16x8, *(const short8*)qp);
    aq1 = __builtin_bit_cast(bf16x8, *(const short8*)(qp + 32));
  }

  v4f oacc[4];
  #pragma unroll
  for (int i = 0; i < 4; i++) oacc[i] = (v4f){0.f, 0.f, 0.f, 0.f};

  const int krow = tid >> 2, kd0 = (tid & 3) * 16;
  const int vr0 = (tid & 31) * 2, vc0 = (tid >> 5) * 8;

  for (int t = z; t <= qt; t += 4){
    int t0 = t * 64;
    __syncthreads();
    {
      const u16* kp = projh + (bS + t0 + krow) * P_ + koff + kd0;
      short8 k0 = *(const short8*)kp;
      short8 k1 = *(const short8*)(kp + 8);
      *(short8*)&ks[krow*72 + kd0]     = k0;
      *(short8*)&ks[krow*72 + kd0 + 8] = k1;
    }
    {
      const u16* vp = projh + (bS + t0 + vr0) * P_ + voff + vc0;
      short8 va = *(const short8*)vp;
      short8 vb = *(const short8*)(vp + P_);
      #pragma unroll
      for (int i = 0; i < 8; i++){
        u32 pk = (u32)(u16)va[i] | ((u32)(u16)vb[i] << 16);
        vs[(vc0 + i)*36 + (vr0 >> 1)] = pk;
      }
    }
    __syncthreads();

    v4f sacc[4];
    #pragma unroll
    for (int i = 0; i < 4; i++) sacc[i] = (v4f){0.f, 0.f, 0.f, 0.f};
    #pragma unroll
    for (int ns = 0; ns < 4; ns++){
      bf16x8 bk0 = __builtin_bit_cast(bf16x8, *(const short8*)&ks[(ns*16 + l15)*72 + quad*8]);
      bf16x8 bk1 = __builtin_bit_cast(bf16x8, *(const short8*)&ks[(ns*16 + l15)*72 + 32 + quad*8]);
      sacc[ns] = __builtin_amdgcn_mfma_f32_16x16x32_bf16(aq0, bk0, sacc[ns], 0, 0, 0);
      sacc[ns] = __builtin_amdgcn_mfma_f32_16x16x32_bf16(aq1, bk1, sacc[ns], 0, 0, 0);
    }

    bool diag = (t == qt);
    #pragma unroll
    for (int ns = 0; ns < 4; ns++){
      #pragma unroll
      for (int r = 0; r < 4; r++){
        int rl = w*16 + quad*4 + r;
        int cl = ns*16 + l15;
        float p = silu(sacc[ns][r]) * (1.0f / S_);
        if (diag && cl > rl) p = 0.0f;
        Ps[rl*68 + cl] = p;
      }
    }
    #pragma unroll
    for (int kst = 0; kst < 2; kst++){
      const float* pp = &Ps[(w*16 + l15)*68 + kst*32 + quad*8];
      v4f p0 = *(const v4f*)pp;
      v4f p1 = *(const v4f*)(pp + 4);
      short8 aps;
      aps[0]=(short)f2bfu(p0[0]); aps[1]=(short)f2bfu(p0[1]);
      aps[2]=(short)f2bfu(p0[2]); aps[3]=(short)f2bfu(p0[3]);
      aps[4]=(short)f2bfu(p1[0]); aps[5]=(short)f2bfu(p1[1]);
      aps[6]=(short)f2bfu(p1[2]); aps[7]=(short)f2bfu(p1[3]);
      bf16x8 ap = __builtin_bit_cast(bf16x8, aps);
      #pragma unroll
      for (int ds = 0; ds < 4; ds++){
        bf16x8 bv = __builtin_bit_cast(bf16x8,
            *(const short8*)&vs[(ds*16 + l15)*36 + kst*16 + quad*4]);
        oacc[ds] = __builtin_amdgcn_mfma_f32_16x16x32_bf16(ap, bv, oacc[ds], 0, 0, 0);
      }
    }
  }

  // epilogue: accumulate raw O partials (round-4-validated address mapping)
  #pragma unroll
  for (int r = 0; r < 4; r++){
    int sg = s0 + w*16 + quad*4 + r;
    float* op = opart + (bS + sg) * (size_t)F_ + hh*64 + l15;
    #pragma unroll
    for (int ds = 0; ds < 4; ds++)
      atomicAdd(op + ds*16, oacc[ds][r]);
  }
}

// ---- 64-dim no-affine norm + u-gate: opart fp32 -> udot bf16 ----
// one wave per row; lane: head = lane>>3, seg = lane&7 (8 elems each)
__global__ __launch_bounds__(256) void norm_gate_kernel(const float* __restrict__ opart,
    const u16* __restrict__ projh, u16* __restrict__ udot){
  int w = threadIdx.x >> 6, lane = threadIdx.x & 63;
  int sg = blockIdx.x * 4 + w;
  int hh = lane >> 3, seg = lane & 7;
  const float* op = opart + (size_t)sg * F_ + hh*64 + seg*8;
  v4f e0 = *(const v4f*)op;
  v4f e1 = *(const v4f*)(op + 4);
  float s  = e0[0]+e0[1]+e0[2]+e0[3] + e1[0]+e1[1]+e1[2]+e1[3];
  float sq = e0[0]*e0[0]+e0[1]*e0[1]+e0[2]*e0[2]+e0[3]*e0[3]
           + e1[0]*e1[0]+e1[1]*e1[1]+e1[2]*e1[2]+e1[3]*e1[3];
  #pragma unroll
  for (int m = 1; m < 8; m <<= 1){
    s  += __shfl_xor(s, m, 64);
    sq += __shfl_xor(sq, m, 64);
  }
  float mu = s * (1.0f/64.0f);
  float var = sq * (1.0f/64.0f) - mu*mu;
  float rs = rsqrtf(var + 1e-6f);
  const u16* up = projh + (size_t)sg * P_ + hh*64 + seg*8;   // u section offset hh*64
  short8 uv = *(const short8*)up;
  short8 ov;
  #pragma unroll
  for (int e = 0; e < 4; e++)
    ov[e] = (short)f2bfu((e0[e] - mu) * rs * bf2f((u16)uv[e]));
  #pragma unroll
  for (int e = 0; e < 4; e++)
    ov[4+e] = (short)f2bfu((e1[e] - mu) * rs * bf2f((u16)uv[4+e]));
  *(short8*)(udot + (size_t)sg * F_ + hh*64 + seg*8) = ov;
}

extern "C" void kernel_launch(void* const* d_in, const int* in_sizes, int n_in,
                              void* d_out, int out_size, void* d_ws, size_t ws_size,
                              hipStream_t stream){
  (void)in_sizes; (void)n_in; (void)out_size; (void)ws_size;
  const float* x     = (const float*)d_in[0];
  // d_in[1] = attn_mask (causal tril) -- hardcoded
  const float* uvqk  = (const float*)d_in[2];
  const float* o_w   = (const float*)d_in[3];
  const float* o_b   = (const float*)d_in[4];
  const float* ln_w  = (const float*)d_in[5];
  const float* ln_b  = (const float*)d_in[6];
  const float* lln_w = (const float*)d_in[7];
  const float* lln_b = (const float*)d_in[8];
  float* out = (float*)d_out;

  char* ws = (char*)d_ws;
  float* xf    = (float*)ws;                          // 16 MB
  u16*   h     = (u16*)(ws + (16u<<20));              //  8 MB
  u16*   udot  = (u16*)(ws + (24u<<20));              //  4 MB
  u16*   projh = (u16*)(ws + (28u<<20));              // 16 MB
  u16*   uvqkT = (u16*)(ws + (44u<<20));              //  8 MB
  u16*   owh   = (u16*)(ws + (52u<<20));              //  2 MB
  float* opart = (float*)(ws + (54u<<20));            //  8 MB

  cvt_kernel<<<R_ * D_ / 1024, 256, 0, stream>>>(x, xf);
  cvt_uvqkT_kernel<<<dim3(P_/32, D_/32, L_), 256, 0, stream>>>(uvqk, uvqkT);
  cvt_bf16_kernel<<<L_ * D_ * F_ / 1024, 256, 0, stream>>>(o_w, owh);
  for (int l = 0; l < L_; l++){
    ln_kernel<<<R_, 256, 0, stream>>>(xf, ln_w + l * D_, ln_b + l * D_, h, 1e-6f, 1);
    gemm_silu_mfma<<<dim3(P_/128, R_/128), 256, 0, stream>>>(
        h, uvqkT + (size_t)l * P_ * D_, projh);
    zero_kernel<<<R_ * F_ / 1024, 256, 0, stream>>>(opart);
    attn_kernel<<<dim3(S_/64, B_*H_, 4), 256, 0, stream>>>(projh, opart);
    norm_gate_kernel<<<R_/4, 256, 0, stream>>>(opart, projh, udot);
    gemm_add_mfma<<<dim3(D_/128, R_/128), 256, 0, stream>>>(
        udot, owh + (size_t)l * D_ * F_, o_b + l * D_, xf);
  }
  ln_kernel<<<R_, 256, 0, stream>>>(xf, lln_w, lln_b, out, 1e-8f, 0);
}

// Round 8
// 338.108 us; speedup vs baseline: 6.2962x; 1.0226x over previous
//
#include <hip/hip_runtime.h>

// HSTU block, B=2 S=2048 D=1024 H=8 head=64 L=2. Inputs/outputs fp32.
// ws (62 MB): xf f32(16M) | h bf16(8M) | udot bf16(4M) | projh bf16(16M)
//           | uvqkT bf16(8M) | owh bf16(2M) | opart f32(8M)
#define B_ 2
#define S_ 2048
#define D_ 1024
#define H_ 8
#define L_ 2
#define P_ 2048   // proj dim
#define F_ 512    // DL*H
#define R_ (B_*S_)

typedef unsigned short u16;
typedef unsigned int u32;
typedef __bf16 bf16;
typedef bf16 bf16x8 __attribute__((ext_vector_type(8)));
typedef short short8 __attribute__((ext_vector_type(8)));
typedef float v4f __attribute__((ext_vector_type(4)));

__device__ __forceinline__ float silu(float x){ return x / (1.0f + __expf(-x)); }
__device__ __forceinline__ float bf2f(u16 u){
  union { u32 i; float f; } x; x.i = ((u32)u) << 16; return x.f;
}
__device__ __forceinline__ u16 f2bfu(float f){
  union { float f; u32 i; } x; x.f = f;
  u32 r = x.i + 0x7fff + ((x.i >> 16) & 1);   // RNE
  return (u16)(r >> 16);
}
__device__ __forceinline__ void gload16(const u16* g, u16* l){
  __builtin_amdgcn_global_load_lds(
      (const __attribute__((address_space(1))) void*)g,
      (__attribute__((address_space(3))) void*)l, 16, 0, 0);
}

// ---- x copy ----
__global__ __launch_bounds__(256) void cvt_kernel(const float* __restrict__ x, float* __restrict__ xf){
  int i = (blockIdx.x * 256 + threadIdx.x) * 4;
  *(float4*)(xf + i) = *(const float4*)(x + i);
}

// ---- zero fp32 buffer ----
__global__ __launch_bounds__(256) void zero_kernel(float* __restrict__ p){
  int i = (blockIdx.x * 256 + threadIdx.x) * 4;
  *(float4*)(p + i) = make_float4(0.f, 0.f, 0.f, 0.f);
}

// ---- fp32 -> bf16 elementwise (o_w) ----
__global__ __launch_bounds__(256) void cvt_bf16_kernel(const float* __restrict__ src, u16* __restrict__ dst){
  int i = (blockIdx.x * 256 + threadIdx.x) * 4;
  float4 v = *(const float4*)(src + i);
  ushort4 o; o.x = f2bfu(v.x); o.y = f2bfu(v.y); o.z = f2bfu(v.z); o.w = f2bfu(v.w);
  *(ushort4*)(dst + i) = o;
}

// ---- uvqk (L,D,P) f32 -> uvqkT (L,P,D) bf16 ----
__global__ __launch_bounds__(256) void cvt_uvqkT_kernel(const float* __restrict__ uvqk, u16* __restrict__ ot){
  __shared__ float t[32][33];
  int l = blockIdx.z;
  int p0 = blockIdx.x * 32, d0 = blockIdx.y * 32;
  int tx = threadIdx.x & 31, ty = threadIdx.x >> 5;   // ty: 8 rows/pass
  const float* src = uvqk + ((size_t)l * D_ + d0) * P_ + p0;
  #pragma unroll
  for (int s = 0; s < 4; s++)
    t[ty + s*8][tx] = src[(size_t)(ty + s*8) * P_ + tx];
  __syncthreads();
  u16* dst = ot + ((size_t)l * P_ + p0) * D_ + d0;
  #pragma unroll
  for (int s = 0; s < 4; s++)
    dst[(size_t)(ty + s*8) * D_ + tx] = f2bfu(t[tx][ty + s*8]);
}

// ---- LayerNorm over D=1024; one block per row; bf16 or fp32 out ----
__global__ __launch_bounds__(256) void ln_kernel(const float* __restrict__ xf,
    const float* __restrict__ w, const float* __restrict__ b,
    void* __restrict__ outp, float eps, int out_bf16){
  int row = blockIdx.x, tid = threadIdx.x;
  const float* xr = xf + (size_t)row * D_;
  float4 v = *(const float4*)(xr + tid * 4);
  float s  = v.x + v.y + v.z + v.w;
  float sq = v.x*v.x + v.y*v.y + v.z*v.z + v.w*v.w;
  #pragma unroll
  for (int off = 32; off; off >>= 1){ s += __shfl_down(s, off); sq += __shfl_down(sq, off); }
  __shared__ float red[8];
  __shared__ float stats[2];
  int wid = tid >> 6;
  if ((tid & 63) == 0){ red[wid] = s; red[4 + wid] = sq; }
  __syncthreads();
  if (tid == 0){
    float S1 = red[0] + red[1] + red[2] + red[3];
    float S2 = red[4] + red[5] + red[6] + red[7];
    float mu = S1 * (1.0f / D_);
    float var = S2 * (1.0f / D_) - mu * mu;
    stats[0] = mu; stats[1] = rsqrtf(var + eps);
  }
  __syncthreads();
  float mu = stats[0], rs = stats[1];
  int i = tid * 4;
  float4 wv = *(const float4*)(w + i);
  float4 bv = *(const float4*)(b + i);
  float o0 = (v.x - mu) * rs * wv.x + bv.x;
  float o1 = (v.y - mu) * rs * wv.y + bv.y;
  float o2 = (v.z - mu) * rs * wv.z + bv.z;
  float o3 = (v.w - mu) * rs * wv.w + bv.w;
  if (out_bf16){
    ushort4 o; o.x = f2bfu(o0); o.y = f2bfu(o1); o.z = f2bfu(o2); o.w = f2bfu(o3);
    *(ushort4*)((u16*)outp + (size_t)row * D_ + i) = o;
  } else {
    *(float4*)((float*)outp + (size_t)row * D_ + i) = make_float4(o0, o1, o2, o3);
  }
}

// ---- MFMA GEMM core: C(128x128) = A(128xK) @ Bt(128xK)^T, bf16 in, f32 acc ----
template<int KDIM>
__device__ __forceinline__ void gemm_mfma_core(const u16* __restrict__ A,
    const u16* __restrict__ Bt, u16* As, u16* Bs, int m0, int n0, v4f acc[4][4]){
  int tid = threadIdx.x;
  int w = tid >> 6, lane = tid & 63;
  int wm = w >> 1, wn = w & 1, quad = lane >> 4, l15 = lane & 15;
  int srow = lane >> 2, skoct = (lane & 3) * 8;
  for (int kt = 0; kt < KDIM; kt += 32){
    __syncthreads();
    #pragma unroll
    for (int s = 0; s < 2; s++){
      int g = w * 2 + s;
      gload16(A  + (size_t)(m0 + g*16 + srow) * KDIM + kt + skoct, As + g*512);
      gload16(Bt + (size_t)(n0 + g*16 + srow) * KDIM + kt + skoct, Bs + g*512);
    }
    __syncthreads();
    short8 af[4], bfr[4];
    #pragma unroll
    for (int i = 0; i < 4; i++)
      af[i] = *(const short8*)&As[(wm*64 + i*16 + l15)*32 + quad*8];
    #pragma unroll
    for (int j = 0; j < 4; j++)
      bfr[j] = *(const short8*)&Bs[(wn*64 + j*16 + l15)*32 + quad*8];
    #pragma unroll
    for (int i = 0; i < 4; i++)
      #pragma unroll
      for (int j = 0; j < 4; j++)
        acc[i][j] = __builtin_amdgcn_mfma_f32_16x16x32_bf16(
            __builtin_bit_cast(bf16x8, af[i]), __builtin_bit_cast(bf16x8, bfr[j]),
            acc[i][j], 0, 0, 0);
  }
}

// ---- projh = silu(h @ uvqk) -> bf16 ----
__global__ __launch_bounds__(256) void gemm_silu_mfma(const u16* __restrict__ A,
    const u16* __restrict__ Bt, u16* __restrict__ C){
  __shared__ u16 As[128*32], Bs[128*32];
  v4f acc[4][4];
  #pragma unroll
  for (int i = 0; i < 4; i++)
    #pragma unroll
    for (int j = 0; j < 4; j++) acc[i][j] = (v4f){0.f,0.f,0.f,0.f};
  int m0 = blockIdx.y * 128, n0 = blockIdx.x * 128;
  gemm_mfma_core<D_>(A, Bt, As, Bs, m0, n0, acc);
  int tid = threadIdx.x, w = tid >> 6, lane = tid & 63;
  int wm = w >> 1, wn = w & 1, quad = lane >> 4, l15 = lane & 15;
  #pragma unroll
  for (int i = 0; i < 4; i++)
    #pragma unroll
    for (int r = 0; r < 4; r++){
      int m = m0 + wm*64 + i*16 + quad*4 + r;
      u16* cp = C + (size_t)m * P_ + n0 + wn*64 + l15;
      #pragma unroll
      for (int j = 0; j < 4; j++)
        cp[j*16] = f2bfu(silu(acc[i][j][r]));
    }
}

// ---- xf += udot @ owh^T + o_b ----
__global__ __launch_bounds__(256) void gemm_add_mfma(const u16* __restrict__ A,
    const u16* __restrict__ Bt, const float* __restrict__ bias, float* __restrict__ X){
  __shared__ u16 As[128*32], Bs[128*32];
  v4f acc[4][4];
  #pragma unroll
  for (int i = 0; i < 4; i++)
    #pragma unroll
    for (int j = 0; j < 4; j++) acc[i][j] = (v4f){0.f,0.f,0.f,0.f};
  int m0 = blockIdx.y * 128, n0 = blockIdx.x * 128;
  gemm_mfma_core<F_>(A, Bt, As, Bs, m0, n0, acc);
  int tid = threadIdx.x, w = tid >> 6, lane = tid & 63;
  int wm = w >> 1, wn = w & 1, quad = lane >> 4, l15 = lane & 15;
  float bj[4];
  #pragma unroll
  for (int j = 0; j < 4; j++) bj[j] = bias[n0 + wn*64 + j*16 + l15];
  #pragma unroll
  for (int i = 0; i < 4; i++)
    #pragma unroll
    for (int r = 0; r < 4; r++){
      int m = m0 + wm*64 + i*16 + quad*4 + r;
      float* xp = X + (size_t)m * D_ + n0 + wn*64 + l15;
      #pragma unroll
      for (int j = 0; j < 4; j++)
        xp[j*16] += acc[i][j][r] + bj[j];
    }
}

// ---- MFMA bf16 causal silu-attention, kt-split partials -> opart fp32 ----
// Round-7 dataflow extended to 128 q-rows/block: each wave runs its verbatim
// round-7 role for two 64-row q-halves (qh=0,1; row offset +qh*64). Ps is
// bf16 (stride 72 u16, 16B-aligned rows): f2bfu at write, ds_read_b128
// readback = PV A-frag directly. grid (S/128, B*H, 4); t strides by 4 (z).
__global__ __launch_bounds__(256) void attn_kernel(const u16* __restrict__ projh,
                                                   float* __restrict__ opart){
  __shared__ u16  ks[64*72];
  __shared__ u32  vs[64*36];
  __shared__ u16  Ps[128*72];      // bf16 scores [qrow 0..127][kt 0..63]
  int qt = 15 - (int)blockIdx.x;   // heavy tiles first (128-row q-tiles)
  int z  = blockIdx.z;             // kt-split 0..3
  int bh = blockIdx.y;
  int b = bh >> 3, hh = bh & 7;
  int tid = threadIdx.x;
  int w = tid >> 6, lane = tid & 63, quad = lane >> 4, l15 = lane & 15;
  int s0 = qt * 128;
  const size_t bS = (size_t)b * S_;
  const int voff = F_ + hh*64, qoff = 2*F_ + hh*64, koff = 3*F_ + hh*64;

  bf16x8 aq[2][2];
  #pragma unroll
  for (int qh = 0; qh < 2; qh++){
    const u16* qp = projh + (bS + s0 + qh*64 + w*16 + l15) * P_ + qoff + quad*8;
    aq[qh][0] = __builtin_bit_cast(bf16x8, *(const short8*)qp);
    aq[qh][1] = __builtin_bit_cast(bf16x8, *(const short8*)(qp + 32));
  }

  v4f oacc[2][4];
  #pragma unroll
  for (int qh = 0; qh < 2; qh++)
    #pragma unroll
    for (int i = 0; i < 4; i++) oacc[qh][i] = (v4f){0.f, 0.f, 0.f, 0.f};

  const int krow = tid >> 2, kd0 = (tid & 3) * 16;
  const int vr0 = (tid & 31) * 2, vc0 = (tid >> 5) * 8;
  int ttop = 2*qt + 1;

  for (int t = z; t <= ttop; t += 4){
    int t0 = t * 64;
    __syncthreads();
    { // stage k-tile row-major padded (round-7 verbatim)
      const u16* kp = projh + (bS + t0 + krow) * P_ + koff + kd0;
      short8 k0 = *(const short8*)kp;
      short8 k1 = *(const short8*)(kp + 8);
      *(short8*)&ks[krow*72 + kd0]     = k0;
      *(short8*)&ks[krow*72 + kd0 + 8] = k1;
    }
    { // stage v-tile transposed + pair-packed (round-7 verbatim)
      const u16* vp = projh + (bS + t0 + vr0) * P_ + voff + vc0;
      short8 va = *(const short8*)vp;
      short8 vb = *(const short8*)(vp + P_);
      #pragma unroll
      for (int i = 0; i < 8; i++){
        u32 pk = (u32)(u16)va[i] | ((u32)(u16)vb[i] << 16);
        vs[(vc0 + i)*36 + (vr0 >> 1)] = pk;
      }
    }
    __syncthreads();

    #pragma unroll
    for (int qh = 0; qh < 2; qh++){
      int dtile = 2*qt + qh;          // this q-half's diagonal tile
      if (t > dtile) continue;        // fully masked (qh=0 at t=ttop)
      v4f sacc[4];
      #pragma unroll
      for (int i = 0; i < 4; i++) sacc[i] = (v4f){0.f, 0.f, 0.f, 0.f};
      #pragma unroll
      for (int ns = 0; ns < 4; ns++){
        bf16x8 bk0 = __builtin_bit_cast(bf16x8, *(const short8*)&ks[(ns*16 + l15)*72 + quad*8]);
        bf16x8 bk1 = __builtin_bit_cast(bf16x8, *(const short8*)&ks[(ns*16 + l15)*72 + 32 + quad*8]);
        sacc[ns] = __builtin_amdgcn_mfma_f32_16x16x32_bf16(aq[qh][0], bk0, sacc[ns], 0, 0, 0);
        sacc[ns] = __builtin_amdgcn_mfma_f32_16x16x32_bf16(aq[qh][1], bk1, sacc[ns], 0, 0, 0);
      }

      bool diag = (t == dtile);
      #pragma unroll
      for (int ns = 0; ns < 4; ns++){
        #pragma unroll
        for (int r = 0; r < 4; r++){
          int rl = w*16 + quad*4 + r;     // local row within this 64-row q-half
          int cl = ns*16 + l15;
          float p = silu(sacc[ns][r]) * (1.0f / S_);
          if (diag && cl > rl) p = 0.0f;
          Ps[(qh*64 + rl)*72 + cl] = f2bfu(p);
        }
      }
      // wave-private bf16 readback = PV A-frag directly
      #pragma unroll
      for (int kst = 0; kst < 2; kst++){
        short8 aps = *(const short8*)&Ps[(qh*64 + w*16 + l15)*72 + kst*32 + quad*8];
        bf16x8 ap = __builtin_bit_cast(bf16x8, aps);
        #pragma unroll
        for (int ds = 0; ds < 4; ds++){
          bf16x8 bv = __builtin_bit_cast(bf16x8,
              *(const short8*)&vs[(ds*16 + l15)*36 + kst*16 + quad*4]);
          oacc[qh][ds] = __builtin_amdgcn_mfma_f32_16x16x32_bf16(ap, bv, oacc[qh][ds], 0, 0, 0);
        }
      }
    }
  }

  // epilogue: accumulate raw O partials (round-7-validated address mapping)
  #pragma unroll
  for (int qh = 0; qh < 2; qh++)
    #pragma unroll
    for (int r = 0; r < 4; r++){
      int sg = s0 + qh*64 + w*16 + quad*4 + r;
      float* op = opart + (bS + sg) * (size_t)F_ + hh*64 + l15;
      #pragma unroll
      for (int ds = 0; ds < 4; ds++)
        atomicAdd(op + ds*16, oacc[qh][ds][r]);
    }
}

// ---- 64-dim no-affine norm + u-gate: opart fp32 -> udot bf16 ----
__global__ __launch_bounds__(256) void norm_gate_kernel(const float* __restrict__ opart,
    const u16* __restrict__ projh, u16* __restrict__ udot){
  int w = threadIdx.x >> 6, lane = threadIdx.x & 63;
  int sg = blockIdx.x * 4 + w;
  int hh = lane >> 3, seg = lane & 7;
  const float* op = opart + (size_t)sg * F_ + hh*64 + seg*8;
  v4f e0 = *(const v4f*)op;
  v4f e1 = *(const v4f*)(op + 4);
  float s  = e0[0]+e0[1]+e0[2]+e0[3] + e1[0]+e1[1]+e1[2]+e1[3];
  float sq = e0[0]*e0[0]+e0[1]*e0[1]+e0[2]*e0[2]+e0[3]*e0[3]
           + e1[0]*e1[0]+e1[1]*e1[1]+e1[2]*e1[2]+e1[3]*e1[3];
  #pragma unroll
  for (int m = 1; m < 8; m <<= 1){
    s  += __shfl_xor(s, m, 64);
    sq += __shfl_xor(sq, m, 64);
  }
  float mu = s * (1.0f/64.0f);
  float var = sq * (1.0f/64.0f) - mu*mu;
  float rs = rsqrtf(var + 1e-6f);
  const u16* up = projh + (size_t)sg * P_ + hh*64 + seg*8;
  short8 uv = *(const short8*)up;
  short8 ov;
  #pragma unroll
  for (int e = 0; e < 4; e++)
    ov[e] = (short)f2bfu((e0[e] - mu) * rs * bf2f((u16)uv[e]));
  #pragma unroll
  for (int e = 0; e < 4; e++)
    ov[4+e] = (short)f2bfu((e1[e] - mu) * rs * bf2f((u16)uv[4+e]));
  *(short8*)(udot + (size_t)sg * F_ + hh*64 + seg*8) = ov;
}

extern "C" void kernel_launch(void* const* d_in, const int* in_sizes, int n_in,
                              void* d_out, int out_size, void* d_ws, size_t ws_size,
                              hipStream_t stream){
  (void)in_sizes; (void)n_in; (void)out_size; (void)ws_size;
  const float* x     = (const float*)d_in[0];
  // d_in[1] = attn_mask (causal tril) -- hardcoded
  const float* uvqk  = (const float*)d_in[2];
  const float* o_w   = (const float*)d_in[3];
  const float* o_b   = (const float*)d_in[4];
  const float* ln_w  = (const float*)d_in[5];
  const float* ln_b  = (const float*)d_in[6];
  const float* lln_w = (const float*)d_in[7];
  const float* lln_b = (const float*)d_in[8];
  float* out = (float*)d_out;

  char* ws = (char*)d_ws;
  float* xf    = (float*)ws;                          // 16 MB
  u16*   h     = (u16*)(ws + (16u<<20));              //  8 MB
  u16*   udot  = (u16*)(ws + (24u<<20));              //  4 MB
  u16*   projh = (u16*)(ws + (28u<<20));              // 16 MB
  u16*   uvqkT = (u16*)(ws + (44u<<20));              //  8 MB
  u16*   owh   = (u16*)(ws + (52u<<20));              //  2 MB
  float* opart = (float*)(ws + (54u<<20));            //  8 MB

  cvt_kernel<<<R_ * D_ / 1024, 256, 0, stream>>>(x, xf);
  cvt_uvqkT_kernel<<<dim3(P_/32, D_/32, L_), 256, 0, stream>>>(uvqk, uvqkT);
  cvt_bf16_kernel<<<L_ * D_ * F_ / 1024, 256, 0, stream>>>(o_w, owh);
  for (int l = 0; l < L_; l++){
    ln_kernel<<<R_, 256, 0, stream>>>(xf, ln_w + l * D_, ln_b + l * D_, h, 1e-6f, 1);
    gemm_silu_mfma<<<dim3(P_/128, R_/128), 256, 0, stream>>>(
        h, uvqkT + (size_t)l * P_ * D_, projh);
    zero_kernel<<<R_ * F_ / 1024, 256, 0, stream>>>(opart);
    attn_kernel<<<dim3(S_/128, B_*H_, 4), 256, 0, stream>>>(projh, opart);
    norm_gate_kernel<<<R_/4, 256, 0, stream>>>(opart, projh, udot);
    gemm_add_mfma<<<dim3(D_/128, R_/128), 256, 0, stream>>>(
        udot, owh + (size_t)l * D_ * F_, o_b + l * D_, xf);
  }
  ln_kernel<<<R_, 256, 0, stream>>>(xf, lln_w, lln_b, out, 1e-8f, 0);
}